// Round 1
// baseline (732.382 us; speedup 1.0000x reference)
//
#include <hip/hip_runtime.h>
#include <hip/hip_bf16.h>

typedef __bf16 bf16;
typedef __attribute__((ext_vector_type(4))) __bf16 bf16x4;
typedef __attribute__((ext_vector_type(8))) __bf16 bf16x8;
typedef __attribute__((ext_vector_type(4))) float f32x4;

#define MFMA(a,b,c) __builtin_amdgcn_mfma_f32_16x16x32_bf16(a,b,c,0,0,0)

// ---- convert x (f32 -> bf16), 4 elements/thread ----
__global__ __launch_bounds__(256) void convert_x_kernel(const float* __restrict__ x,
                                                        bf16* __restrict__ xb) {
    int i = blockIdx.x * 256 + threadIdx.x;
    float4 v = ((const float4*)x)[i];
    bf16x4 o = { (bf16)v.x, (bf16)v.y, (bf16)v.z, (bf16)v.w };
    ((bf16x4*)xb)[i] = o;
}

// ---- transpose + convert one 768x768 weight: Wt[n][k] = (bf16)W[k][n] ----
__global__ __launch_bounds__(1024) void convert_w_kernel(const float* __restrict__ W,
                                                         bf16* __restrict__ Wt) {
    __shared__ float tile[32][33];
    int k0 = blockIdx.x * 32, n0 = blockIdx.y * 32;
    int tx = threadIdx.x & 31, ty = threadIdx.x >> 5;
    tile[ty][tx] = W[(k0 + ty) * 768 + n0 + tx];
    __syncthreads();
    Wt[(n0 + ty) * 768 + k0 + tx] = (bf16)tile[tx][ty];
}

// ---- C = A[M,768] @ Bt[N,768]^T, 64x64 tile, 4 waves (2x2), 16x16x32 MFMA ----
// mode 0: q (scale 0.125, head layout [b,h,n,d] bf16)
// mode 1: k (head layout bf16)
// mode 2: v (transposed head layout [b,h,d,n] bf16)
// mode 3: f32 flat [8192,768] to d_out
__global__ __launch_bounds__(256) void gemm_kernel(const bf16* __restrict__ A,
                                                   const bf16* __restrict__ Bt,
                                                   void* __restrict__ dst, int mode) {
    __shared__ bf16 As[64][40];
    __shared__ bf16 Bs[64][40];
    const int K = 768;
    int m0 = blockIdx.x * 64, n0 = blockIdx.y * 64;
    int tid = threadIdx.x, lane = tid & 63, w = tid >> 6;
    int wr = w >> 1, wc = w & 1;
    int lrow = tid >> 2, lch = (tid & 3) * 8;
    int fr = lane & 15, fg = lane >> 4;
    f32x4 acc[2][2] = {};
    for (int k0 = 0; k0 < K; k0 += 32) {
        __syncthreads();
        *(bf16x8*)&As[lrow][lch] = *(const bf16x8*)&A[(size_t)(m0 + lrow) * K + k0 + lch];
        *(bf16x8*)&Bs[lrow][lch] = *(const bf16x8*)&Bt[(size_t)(n0 + lrow) * K + k0 + lch];
        __syncthreads();
        bf16x8 af[2], bfr[2];
        for (int i = 0; i < 2; i++) af[i]  = *(const bf16x8*)&As[wr*32 + i*16 + fr][fg*8];
        for (int j = 0; j < 2; j++) bfr[j] = *(const bf16x8*)&Bs[wc*32 + j*16 + fr][fg*8];
        for (int i = 0; i < 2; i++)
            for (int j = 0; j < 2; j++)
                acc[i][j] = MFMA(af[i], bfr[j], acc[i][j]);
    }
    for (int i = 0; i < 2; i++) for (int j = 0; j < 2; j++) for (int r = 0; r < 4; r++) {
        int grow = m0 + wr*32 + i*16 + fg*4 + r;   // C/D: row=(l>>4)*4+r
        int gcol = n0 + wc*32 + j*16 + fr;          //      col=l&15
        float v = acc[i][j][r];
        if (mode == 3) {
            ((float*)dst)[(size_t)grow * 768 + gcol] = v;
        } else {
            int b = grow >> 10, np = grow & 1023;
            int h = gcol >> 6, dd = gcol & 63;
            bf16* o = (bf16*)dst;
            if (mode == 0)      o[((size_t)(b*12 + h)*1024 + np)*64 + dd] = (bf16)(v * 0.125f);
            else if (mode == 1) o[((size_t)(b*12 + h)*1024 + np)*64 + dd] = (bf16)v;
            else                o[((size_t)(b*12 + h)*64 + dd)*1024 + np] = (bf16)v;
        }
    }
}

// XOR swizzle at 16B granularity so PV A-fragment reads (16 rows, same col range)
// spread over 8 bank-slots (balanced = LDS floor) instead of 4 (2x serialize).
__device__ inline int saddr(int row, int col) {
    int chunk = (col >> 2) ^ (row & 7);
    return row * 1024 + chunk * 4 + (col & 3);
}

// ---- fused per-head attention: S=qk^T+bias, softmax (attn out f32), O = P@V ----
// grid (96 heads, 64 q-slabs of 16), 256 threads (4 waves)
__global__ __launch_bounds__(256) void attn_kernel(const bf16* __restrict__ qb,
                                                   const bf16* __restrict__ kb,
                                                   const bf16* __restrict__ vt,
                                                   const float* __restrict__ bias,
                                                   float* __restrict__ attn,
                                                   bf16* __restrict__ Ob) {
    __shared__ float S[16 * 1024];   // exactly 64 KB
    int bh = blockIdx.x, q0 = blockIdx.y * 16;
    int tid = threadIdx.x, lane = tid & 63, w = tid >> 6;
    int fr = lane & 15, fg = lane >> 4;
    const bf16* qp = qb + (size_t)bh * 65536;
    const bf16* kp = kb + (size_t)bh * 65536;
    const bf16* vp = vt + (size_t)bh * 65536;
    // Q A-fragments: row = l&15 (query), k = (l>>4)*8 + j, two k-halves of d=64
    bf16x8 qa0 = *(const bf16x8*)&qp[(q0 + fr) * 64 + fg * 8];
    bf16x8 qa1 = *(const bf16x8*)&qp[(q0 + fr) * 64 + 32 + fg * 8];
    // phase 1: S rows [0,16) x keys; wave w covers keys [w*256, w*256+256)
    for (int j = 0; j < 16; j++) {
        int key0 = w * 256 + j * 16;
        bf16x8 kb0 = *(const bf16x8*)&kp[(key0 + fr) * 64 + fg * 8];
        bf16x8 kb1 = *(const bf16x8*)&kp[(key0 + fr) * 64 + 32 + fg * 8];
        f32x4 acc = {};
        acc = MFMA(qa0, kb0, acc);
        acc = MFMA(qa1, kb1, acc);
        for (int r = 0; r < 4; r++) {
            int row = fg * 4 + r, key = key0 + fr;
            S[saddr(row, key)] = acc[r] + bias[(q0 + row) * 1024 + key];
        }
    }
    __syncthreads();
    // phase 2: wave-per-row softmax; wave w does rows {w, w+4, w+8, w+12}
    for (int rr = 0; rr < 4; rr++) {
        int row = rr * 4 + w;
        float vals[16], mx = -1e30f;
        for (int i = 0; i < 16; i++) { vals[i] = S[saddr(row, i*64 + lane)]; mx = fmaxf(mx, vals[i]); }
        for (int off = 32; off; off >>= 1) mx = fmaxf(mx, __shfl_xor(mx, off));
        float sum = 0.f;
        for (int i = 0; i < 16; i++) { vals[i] = __expf(vals[i] - mx); sum += vals[i]; }
        for (int off = 32; off; off >>= 1) sum += __shfl_xor(sum, off);
        float rcp = 1.f / sum;
        float* arow = attn + ((size_t)bh * 1024 + q0 + row) * 1024;
        for (int i = 0; i < 16; i++) {
            float p = vals[i] * rcp;
            S[saddr(row, i*64 + lane)] = p;   // normalized P for PV
            arow[i*64 + lane] = p;            // coalesced f32 attn output
        }
    }
    __syncthreads();
    // phase 3: O[16][64] = P[16][1024] @ v[1024][64]; wave w -> out cols [w*16, w*16+16)
    f32x4 oacc = {};
    for (int kk = 0; kk < 32; kk++) {
        int c0 = kk * 32 + fg * 8;
        f32x4 p0 = *(f32x4*)&S[saddr(fr, c0)];
        f32x4 p1 = *(f32x4*)&S[saddr(fr, c0 + 4)];
        bf16x8 pa;
        pa[0]=(bf16)p0[0]; pa[1]=(bf16)p0[1]; pa[2]=(bf16)p0[2]; pa[3]=(bf16)p0[3];
        pa[4]=(bf16)p1[0]; pa[5]=(bf16)p1[1]; pa[6]=(bf16)p1[2]; pa[7]=(bf16)p1[3];
        bf16x8 vb = *(const bf16x8*)&vp[(w*16 + fr) * 1024 + kk*32 + fg*8];
        oacc = MFMA(pa, vb, oacc);
    }
    int b = bh / 12, h = bh % 12;
    for (int r = 0; r < 4; r++) {
        int row = fg * 4 + r;
        Ob[((size_t)b * 1024 + q0 + row) * 768 + h * 64 + w * 16 + fr] = (bf16)oacc[r];
    }
}

extern "C" void kernel_launch(void* const* d_in, const int* in_sizes, int n_in,
                              void* d_out, int out_size, void* d_ws, size_t ws_size,
                              hipStream_t stream) {
    const float* x    = (const float*)d_in[0];
    const float* Wq   = (const float*)d_in[1];
    const float* Wk   = (const float*)d_in[2];
    const float* Wv   = (const float*)d_in[3];
    const float* Wp   = (const float*)d_in[4];
    const float* bias = (const float*)d_in[5];
    char* ws = (char*)d_ws;
    // ws layout (bytes): x_bf 12.58M | Wt x4 4.72M | q 12.58M | k 12.58M | vT 12.58M | O 12.58M  (~67.6 MB)
    bf16* xb  = (bf16*)(ws + 0);
    bf16* wt  = (bf16*)(ws + 12582912);
    bf16* qbp = (bf16*)(ws + 17301504);
    bf16* kbp = (bf16*)(ws + 29884416);
    bf16* vtp = (bf16*)(ws + 42467328);
    bf16* obp = (bf16*)(ws + 55050240);
    float* out0 = (float*)d_out;
    float* attn = out0 + 6291456;   // outputs concatenated: out [8,1024,768] then attn [8,12,1024,1024]

    convert_x_kernel<<<6144, 256, 0, stream>>>(x, xb);
    const float* Wsrc[4] = {Wq, Wk, Wv, Wp};
    for (int i = 0; i < 4; i++)
        convert_w_kernel<<<dim3(24,24), 1024, 0, stream>>>(Wsrc[i], wt + (size_t)i*589824);
    gemm_kernel<<<dim3(128,12), 256, 0, stream>>>(xb, wt + 0*589824, qbp, 0);
    gemm_kernel<<<dim3(128,12), 256, 0, stream>>>(xb, wt + 1*589824, kbp, 1);
    gemm_kernel<<<dim3(128,12), 256, 0, stream>>>(xb, wt + 2*589824, vtp, 2);
    attn_kernel<<<dim3(96,64), 256, 0, stream>>>(qbp, kbp, vtp, bias, attn, obp);
    gemm_kernel<<<dim3(128,12), 256, 0, stream>>>(obp, wt + 3*589824, out0, 3);
}